// Round 3
// baseline (916.777 us; speedup 1.0000x reference)
//
#include <hip/hip_runtime.h>

#define BATCH 16
#define SEQ   2048
#define DH    128
#define BM    32          // q rows per block (4 waves, all waves share all 32 rows)
#define BN    64          // k cols per tile
#define NT    (SEQ / BN)  // 32 k-tiles

typedef float  f32x4 __attribute__((ext_vector_type(4)));
typedef short  s16x8 __attribute__((ext_vector_type(8)));
typedef short  s16x4 __attribute__((ext_vector_type(4)));
typedef unsigned short u16;

// fp32 -> bf16 round-to-nearest-even
__device__ __forceinline__ short f2bf(float f) {
    union { float f; unsigned u; } a; a.f = f;
    unsigned r = a.u + 0x7FFFu + ((a.u >> 16) & 1u);
    return (short)(r >> 16);
}

__device__ __forceinline__ void gl_lds16(const void* g, void* l) {
    __builtin_amdgcn_global_load_lds(
        (const __attribute__((address_space(1))) void*)g,
        (__attribute__((address_space(3))) void*)l, 16, 0, 0);
}

// ============================================================================
// conv_qk: Q -> bf16 row-major; K -> bf16 tile-contiguous swizzled LDS image;
//          mask -> has_mask flag.  Swizzle: byte-in-tile = (row*256 + d*2) ^ ((row&7)<<4)
// ============================================================================
__global__ __launch_bounds__(256)
void conv_qk(const float* __restrict__ q, const float* __restrict__ k,
             const float* __restrict__ mask, u16* __restrict__ qw,
             char* __restrict__ kw, int* __restrict__ flag) {
    size_t e = ((size_t)blockIdx.x * 256 + threadIdx.x) * 8;

    f32x4 f0 = *(const f32x4*)(q + e);
    f32x4 f1 = *(const f32x4*)(q + e + 4);
    s16x8 w;
    w[0]=f2bf(f0[0]); w[1]=f2bf(f0[1]); w[2]=f2bf(f0[2]); w[3]=f2bf(f0[3]);
    w[4]=f2bf(f1[0]); w[5]=f2bf(f1[1]); w[6]=f2bf(f1[2]); w[7]=f2bf(f1[3]);
    *(s16x8*)(qw + e) = w;

    f0 = *(const f32x4*)(k + e);
    f1 = *(const f32x4*)(k + e + 4);
    w[0]=f2bf(f0[0]); w[1]=f2bf(f0[1]); w[2]=f2bf(f0[2]); w[3]=f2bf(f0[3]);
    w[4]=f2bf(f1[0]); w[5]=f2bf(f1[1]); w[6]=f2bf(f1[2]); w[7]=f2bf(f1[3]);
    int    d0   = (int)(e & 127);
    size_t srow = e >> 7;           // b*2048 + s
    int    row  = (int)(srow & 63);
    size_t tile = srow >> 6;        // b*32 + kt
    *(s16x8*)(kw + (tile << 14) +
              ((((row << 8) + (d0 << 1)) ^ ((row & 7) << 4)))) = w;

    // mask flag
    f0 = *(const f32x4*)(mask + e);
    f1 = *(const f32x4*)(mask + e + 4);
    bool nz = f0[0]!=0.f || f0[1]!=0.f || f0[2]!=0.f || f0[3]!=0.f ||
              f1[0]!=0.f || f1[1]!=0.f || f1[2]!=0.f || f1[3]!=0.f;
    if (__ballot(nz) != 0ull) {
        if ((threadIdx.x & 63) == 0) atomicOr(flag, 1);
    }
}

// ============================================================================
// conv_v: V -> V^T bf16 tile-contiguous swizzled image, one block per 64x128 tile.
//   image byte-in-tile = (d*128 + j*2) ^ ((d&7)<<4) holds V[kt*64+j][d]
// ============================================================================
__global__ __launch_bounds__(256)
void conv_v(const float* __restrict__ v, char* __restrict__ vw) {
    __shared__ u16 lt[64][132];
    const int tid = threadIdx.x;
    const int kt = blockIdx.x, b = blockIdx.y;
    const float* src = v + (((size_t)b * SEQ + kt * 64) << 7);
    #pragma unroll
    for (int i = 0; i < 8; ++i) {
        int c = i * 256 + tid;
        int j = c >> 5, d0 = (c & 31) * 4;
        f32x4 f = *(const f32x4*)(src + (j << 7) + d0);
        s16x4 w4; w4[0]=f2bf(f[0]); w4[1]=f2bf(f[1]); w4[2]=f2bf(f[2]); w4[3]=f2bf(f[3]);
        *(s16x4*)&lt[j][d0] = w4;
    }
    __syncthreads();
    char* dstt = vw + (((size_t)b * NT + kt) << 14);
    #pragma unroll
    for (int i = 0; i < 4; ++i) {
        int c = i * 256 + tid;
        int d = c >> 3, jg = c & 7;
        s16x8 w8;
        #pragma unroll
        for (int s = 0; s < 8; ++s) w8[s] = (short)lt[jg * 8 + s][d];
        *(s16x8*)(dstt + (((d << 7) + jg * 16) ^ ((d & 7) << 4))) = w8;
    }
}

// ============================================================================
// main fused attention kernel, BM=32, 4 blocks/CU.
// LDS 37888B: K@0 (16K, single buf in pass2; dbuf with V region in pass1),
//             V@16384 (16K), P/ls@32768 (5120B; 4 strips of 1280B, row stride 40)
// ============================================================================
#define KOFF 0
#define VOFF 16384
#define POFF 32768

#define STAGE16K(SRC, LOFF) do {                                   \
    const char* _s = (SRC); const int _o = tid * 16;               \
    gl_lds16(_s + _o,         smem + (LOFF) + _o);                 \
    gl_lds16(_s + _o + 4096,  smem + (LOFF) + _o + 4096);          \
    gl_lds16(_s + _o + 8192,  smem + (LOFF) + _o + 8192);          \
    gl_lds16(_s + _o + 12288, smem + (LOFF) + _o + 12288);         \
} while (0)

__global__ __launch_bounds__(256, 4)
void attn_main(const u16* __restrict__ qw, const char* __restrict__ kw,
               const char* __restrict__ vw, const float* __restrict__ mask,
               const int* __restrict__ flag,
               float* __restrict__ out_o, float* __restrict__ out_p) {
    extern __shared__ char smem[];
    const int tid  = threadIdx.x;
    const int wave = tid >> 6, lane = tid & 63, quad = lane >> 4, l16 = lane & 15;
    const int b = blockIdx.y, q0 = blockIdx.x * BM;
    const float CS  = 0.08838834764831845f * 1.4426950408889634f; // scale * log2(e)
    const float L2E = 1.4426950408889634f;
    const int hm = *flag;
    const int sw   = (l16 & 7) << 4;  // read-side XOR swizzle
    const int kcol = wave * 16 + l16; // this wave's k-strip column (QK B-op / P col)

    // ---- Q: all 32 rows of the block in registers (A-op: m=l16, k=quad*8+j)
    s16x8 aq[2][4];
    #pragma unroll
    for (int mt = 0; mt < 2; ++mt) {
        const u16* qp = qw + ((size_t)(b * SEQ + q0 + mt * 16 + l16) << 7);
        #pragma unroll
        for (int s = 0; s < 4; ++s)
            aq[mt][s] = *(const s16x8*)(qp + s * 32 + quad * 8);
    }

    const char* kb = kw + ((size_t)(b * NT) << 14);
    const char* vb = vw + ((size_t)(b * NT) << 14);

    float lsum[2][4];
    #pragma unroll
    for (int mt = 0; mt < 2; ++mt)
        #pragma unroll
        for (int r = 0; r < 4; ++r) lsum[mt][r] = 0.f;

    // =================== Pass 1: strip row-sums of exp (K dbuf over K+V regions) ==
    STAGE16K(kb, KOFF);
    __syncthreads();
    int kof = 0;
    for (int kt = 0; kt < NT; ++kt) {
        if (kt + 1 < NT) STAGE16K(kb + ((size_t)(kt + 1) << 14), kof ^ 16384);
        s16x8 bk[4];
        #pragma unroll
        for (int s = 0; s < 4; ++s)
            bk[s] = *(const s16x8*)(smem + kof +
                (((kcol << 8) + s * 64 + quad * 16) ^ sw));
        f32x4 cm[2];
        __builtin_amdgcn_s_setprio(1);
        #pragma unroll
        for (int mt = 0; mt < 2; ++mt) {
            f32x4 c = {0.f, 0.f, 0.f, 0.f};
            #pragma unroll
            for (int s = 0; s < 4; ++s)
                c = __builtin_amdgcn_mfma_f32_16x16x32_bf16(aq[mt][s], bk[s], c, 0, 0, 0);
            cm[mt] = c;
        }
        __builtin_amdgcn_s_setprio(0);
        #pragma unroll
        for (int mt = 0; mt < 2; ++mt) {
            float mk[4] = {0.f, 0.f, 0.f, 0.f};
            if (hm) {
                #pragma unroll
                for (int r = 0; r < 4; ++r)
                    mk[r] = mask[(size_t)(q0 + mt * 16 + quad * 4 + r) * SEQ
                                 + kt * BN + kcol] * L2E;
            }
            #pragma unroll
            for (int r = 0; r < 4; ++r)
                lsum[mt][r] += exp2f(cm[mt][r] * CS + mk[r]);
        }
        __syncthreads();
        kof ^= 16384;
    }

    // ---- prologue restage of K[0] overlaps the reduction
    STAGE16K(kb, KOFF);

    // ---- combine strips: in-wave over l16, then cross-wave via LDS (at POFF)
    float* ls = (float*)(smem + POFF);   // ls[32][4] f32
    #pragma unroll
    for (int mt = 0; mt < 2; ++mt)
        #pragma unroll
        for (int r = 0; r < 4; ++r) {
            float s = lsum[mt][r];
            s += __shfl_xor(s, 1);
            s += __shfl_xor(s, 2);
            s += __shfl_xor(s, 4);
            s += __shfl_xor(s, 8);
            lsum[mt][r] = s;
        }
    if (l16 == 0) {
        #pragma unroll
        for (int mt = 0; mt < 2; ++mt)
            #pragma unroll
            for (int r = 0; r < 4; ++r)
                ls[(mt * 16 + quad * 4 + r) * 4 + wave] = lsum[mt][r];
    }
    __syncthreads();   // orders ls + drains K[0] DMA
    float linv[2][4];
    #pragma unroll
    for (int mt = 0; mt < 2; ++mt)
        #pragma unroll
        for (int r = 0; r < 4; ++r) {
            f32x4 t = *(const f32x4*)&ls[(mt * 16 + quad * 4 + r) * 4];
            linv[mt][r] = 1.0f / (t[0] + t[1] + t[2] + t[3]);
        }
    __syncthreads();   // ls reads done before P strip writes reuse POFF

    f32x4 acc[2][2];
    #pragma unroll
    for (int amt = 0; amt < 2; ++amt) {
        acc[amt][0] = (f32x4){0.f, 0.f, 0.f, 0.f};
        acc[amt][1] = (f32x4){0.f, 0.f, 0.f, 0.f};
    }

    // =================== Pass 2: P strip -> out_p + LDS, then PV d-strips =========
    for (int kt = 0; kt < NT; ++kt) {
        STAGE16K(vb + ((size_t)kt << 14), VOFF);   // V[kt]; lands during QK phase
        s16x8 bk[4];
        #pragma unroll
        for (int s = 0; s < 4; ++s)
            bk[s] = *(const s16x8*)(smem + KOFF +
                (((kcol << 8) + s * 64 + quad * 16) ^ sw));
        f32x4 cm[2];
        __builtin_amdgcn_s_setprio(1);
        #pragma unroll
        for (int mt = 0; mt < 2; ++mt) {
            f32x4 c = {0.f, 0.f, 0.f, 0.f};
            #pragma unroll
            for (int s = 0; s < 4; ++s)
                c = __builtin_amdgcn_mfma_f32_16x16x32_bf16(aq[mt][s], bk[s], c, 0, 0, 0);
            cm[mt] = c;
        }
        __builtin_amdgcn_s_setprio(0);
        #pragma unroll
        for (int mt = 0; mt < 2; ++mt) {
            float mk[4] = {0.f, 0.f, 0.f, 0.f};
            if (hm) {
                #pragma unroll
                for (int r = 0; r < 4; ++r)
                    mk[r] = mask[(size_t)(q0 + mt * 16 + quad * 4 + r) * SEQ
                                 + kt * BN + kcol] * L2E;
            }
            #pragma unroll
            for (int r = 0; r < 4; ++r) {
                float p = exp2f(cm[mt][r] * CS + mk[r]) * linv[mt][r];
                __builtin_nontemporal_store(p,
                    &out_p[((size_t)(b * SEQ + q0 + mt * 16 + quad * 4 + r) << 11)
                           + kt * BN + kcol]);
                const int pr = mt * 16 + quad * 4 + r;
                // P strip: wave-private 1280B region, row stride 40B (bank-conflict-free)
                *(short*)(smem + POFF + wave * 1280 + pr * 40 + (l16 << 1)) = f2bf(p);
            }
        }
        __syncthreads();   // V landed (all waves), P visible, bk reads done

        if (kt + 1 < NT)   // K[kt+1] into the single K buffer; lands during PV
            STAGE16K(kb + ((size_t)(kt + 1) << 14), KOFF);

        // PV: A = P (strip-packed), B = this wave's 32-d strip of V^T
        __builtin_amdgcn_s_setprio(1);
        #pragma unroll
        for (int s2 = 0; s2 < 2; ++s2) {
            const s16x8 bv0 = *(const s16x8*)(smem + VOFF +
                ((((wave * 32 + l16) << 7) + s2 * 64 + quad * 16) ^ sw));
            const s16x8 bv1 = *(const s16x8*)(smem + VOFF +
                ((((wave * 32 + 16 + l16) << 7) + s2 * 64 + quad * 16) ^ sw));
            const int strip = s2 * 2 + (quad >> 1);
            #pragma unroll
            for (int amt = 0; amt < 2; ++amt) {
                const s16x8 pa = *(const s16x8*)(smem + POFF + strip * 1280 +
                    (amt * 16 + l16) * 40 + ((quad & 1) << 4));
                acc[amt][0] = __builtin_amdgcn_mfma_f32_16x16x32_bf16(pa, bv0, acc[amt][0], 0, 0, 0);
                acc[amt][1] = __builtin_amdgcn_mfma_f32_16x16x32_bf16(pa, bv1, acc[amt][1], 0, 0, 0);
            }
        }
        __builtin_amdgcn_s_setprio(0);
        __syncthreads();   // K[kt+1] landed (all waves), V/P reads done
    }

    // ---- write O (fp32): rows amt*16+quad*4+r, cols wave*32+nt*16+l16
    #pragma unroll
    for (int amt = 0; amt < 2; ++amt)
        #pragma unroll
        for (int nt = 0; nt < 2; ++nt)
            #pragma unroll
            for (int r = 0; r < 4; ++r)
                __builtin_nontemporal_store(acc[amt][nt][r],
                    &out_o[((size_t)(b * SEQ + q0 + amt * 16 + quad * 4 + r) << 7)
                           + wave * 32 + nt * 16 + l16]);
}

extern "C" void kernel_launch(void* const* d_in, const int* in_sizes, int n_in,
                              void* d_out, int out_size, void* d_ws, size_t ws_size,
                              hipStream_t stream) {
    (void)in_sizes; (void)n_in; (void)out_size; (void)ws_size;
    const float* q    = (const float*)d_in[0];
    const float* k    = (const float*)d_in[1];
    const float* v    = (const float*)d_in[2];
    const float* mask = (const float*)d_in[3];
    float* out_o = (float*)d_out;                          // [16,2048,128]
    float* out_p = out_o + (size_t)BATCH * SEQ * DH;       // [16,2048,2048]

    char* ws   = (char*)d_ws;
    u16*  qw   = (u16*)ws;                                 // 8 MiB bf16 Q
    char* kw   = ws + ((size_t)8 << 20);                   // 8 MiB swizzled K tiles
    char* vw   = ws + ((size_t)16 << 20);                  // 8 MiB swizzled V^T tiles
    int*  flag = (int*)(ws + ((size_t)24 << 20));          // has_mask flag

    hipMemsetAsync(flag, 0, 4, stream);
    conv_qk<<<dim3(2048), dim3(256), 0, stream>>>(q, k, mask, qw, kw, flag);
    conv_v<<<dim3(NT, BATCH), dim3(256), 0, stream>>>(v, vw);

    attn_main<<<dim3(SEQ / BM, BATCH), dim3(256), 37888, stream>>>(
        qw, kw, vw, mask, flag, out_o, out_p);
}

// Round 4
// 396.162 us; speedup vs baseline: 2.3141x; 2.3141x over previous
//
#include <hip/hip_runtime.h>

#define BATCH 16
#define SEQ   2048
#define DH    128
#define BM    64          // q rows per block (4 waves)
#define BN    64          // k cols per tile
#define NT    (SEQ / BN)  // 32 k-tiles

typedef float  f32x4 __attribute__((ext_vector_type(4)));
typedef short  s16x8 __attribute__((ext_vector_type(8)));
typedef short  s16x4 __attribute__((ext_vector_type(4)));
typedef unsigned short u16;

// fp32 -> bf16 round-to-nearest-even
__device__ __forceinline__ short f2bf(float f) {
    union { float f; unsigned u; } a; a.f = f;
    unsigned r = a.u + 0x7FFFu + ((a.u >> 16) & 1u);
    return (short)(r >> 16);
}

__device__ __forceinline__ void gl_lds16(const void* g, void* l) {
    __builtin_amdgcn_global_load_lds(
        (const __attribute__((address_space(1))) void*)g,
        (__attribute__((address_space(3))) void*)l, 16, 0, 0);
}

// ============================================================================
// conv_qk: Q -> bf16 row-major; K -> bf16 tile-contiguous swizzled LDS image;
//          mask -> has_mask flag.  Swizzle: byte-in-tile = (row*256 + d*2) ^ ((row&7)<<4)
// ============================================================================
__global__ __launch_bounds__(256)
void conv_qk(const float* __restrict__ q, const float* __restrict__ k,
             const float* __restrict__ mask, u16* __restrict__ qw,
             char* __restrict__ kw, int* __restrict__ flag) {
    size_t e = ((size_t)blockIdx.x * 256 + threadIdx.x) * 8;

    f32x4 f0 = *(const f32x4*)(q + e);
    f32x4 f1 = *(const f32x4*)(q + e + 4);
    s16x8 w;
    w[0]=f2bf(f0[0]); w[1]=f2bf(f0[1]); w[2]=f2bf(f0[2]); w[3]=f2bf(f0[3]);
    w[4]=f2bf(f1[0]); w[5]=f2bf(f1[1]); w[6]=f2bf(f1[2]); w[7]=f2bf(f1[3]);
    *(s16x8*)(qw + e) = w;

    f0 = *(const f32x4*)(k + e);
    f1 = *(const f32x4*)(k + e + 4);
    w[0]=f2bf(f0[0]); w[1]=f2bf(f0[1]); w[2]=f2bf(f0[2]); w[3]=f2bf(f0[3]);
    w[4]=f2bf(f1[0]); w[5]=f2bf(f1[1]); w[6]=f2bf(f1[2]); w[7]=f2bf(f1[3]);
    int    d0   = (int)(e & 127);
    size_t srow = e >> 7;           // b*2048 + s
    int    row  = (int)(srow & 63);
    size_t tile = srow >> 6;        // b*32 + kt
    *(s16x8*)(kw + (tile << 14) +
              ((((row << 8) + (d0 << 1)) ^ ((row & 7) << 4)))) = w;

    // mask flag
    f0 = *(const f32x4*)(mask + e);
    f1 = *(const f32x4*)(mask + e + 4);
    bool nz = f0[0]!=0.f || f0[1]!=0.f || f0[2]!=0.f || f0[3]!=0.f ||
              f1[0]!=0.f || f1[1]!=0.f || f1[2]!=0.f || f1[3]!=0.f;
    if (__ballot(nz) != 0ull) {
        if ((threadIdx.x & 63) == 0) atomicOr(flag, 1);
    }
}

// ============================================================================
// conv_v: V -> V^T bf16 tile-contiguous swizzled image, one block per 64x128 tile.
//   image byte-in-tile = (d*128 + j*2) ^ ((d&7)<<4) holds V[kt*64+j][d]
// ============================================================================
__global__ __launch_bounds__(256)
void conv_v(const float* __restrict__ v, char* __restrict__ vw) {
    __shared__ u16 lt[64][132];
    const int tid = threadIdx.x;
    const int kt = blockIdx.x, b = blockIdx.y;
    const float* src = v + (((size_t)b * SEQ + kt * 64) << 7);
    #pragma unroll
    for (int i = 0; i < 8; ++i) {
        int c = i * 256 + tid;
        int j = c >> 5, d0 = (c & 31) * 4;
        f32x4 f = *(const f32x4*)(src + (j << 7) + d0);
        s16x4 w4; w4[0]=f2bf(f[0]); w4[1]=f2bf(f[1]); w4[2]=f2bf(f[2]); w4[3]=f2bf(f[3]);
        *(s16x4*)&lt[j][d0] = w4;
    }
    __syncthreads();
    char* dstt = vw + (((size_t)b * NT + kt) << 14);
    #pragma unroll
    for (int i = 0; i < 4; ++i) {
        int c = i * 256 + tid;
        int d = c >> 3, jg = c & 7;
        s16x8 w8;
        #pragma unroll
        for (int s = 0; s < 8; ++s) w8[s] = (short)lt[jg * 8 + s][d];
        *(s16x8*)(dstt + (((d << 7) + jg * 16) ^ ((d & 7) << 4))) = w8;
    }
}

// ============================================================================
// main fused attention kernel (BM=64, 2 blocks/CU).
// Dynamic LDS 73728B: K0@0, K1@16K, V0@32K, V1@48K, PP/LS@64K(8KB)
// QK: each wave owns a 16-col K strip (all 64 Q rows in regs).
// PV: each wave owns a 32-d V strip.
// P global store: full-line f32 from LDS bf16 after PV (no partial-line RMW).
// XCD remap: 512 blocks = 8 XCDs x 64; each XCD owns exactly 2 batches.
// ============================================================================
#define KOFF0 0
#define VOFF0 32768
#define POFF  65536

#define STAGE16K(SRC, LOFF) do {                                   \
    const char* _s = (SRC); const int _o = tid * 16;               \
    gl_lds16(_s + _o,         smem + (LOFF) + _o);                 \
    gl_lds16(_s + _o + 4096,  smem + (LOFF) + _o + 4096);          \
    gl_lds16(_s + _o + 8192,  smem + (LOFF) + _o + 8192);          \
    gl_lds16(_s + _o + 12288, smem + (LOFF) + _o + 12288);         \
} while (0)

__global__ __launch_bounds__(256, 2)
void attn_main(const u16* __restrict__ qw, const char* __restrict__ kw,
               const char* __restrict__ vw, const float* __restrict__ mask,
               const int* __restrict__ flag,
               float* __restrict__ out_o, float* __restrict__ out_p) {
    extern __shared__ char smem[];
    const int tid  = threadIdx.x;
    const int wave = tid >> 6, lane = tid & 63, quad = lane >> 4, l16 = lane & 15;

    // XCD-aware bijective remap: lid%8 ~ XCD; give each XCD 2 whole batches.
    const int lid = blockIdx.y * gridDim.x + blockIdx.x;   // 0..511
    const int xcd = lid & 7, wi = lid >> 3;                // wi 0..63
    const int b  = (xcd << 1) | (wi >> 5);                 // 0..15
    const int q0 = (wi & 31) * BM;

    const float CS  = 0.08838834764831845f * 1.4426950408889634f; // scale * log2(e)
    const float L2E = 1.4426950408889634f;
    const int hm = *flag;
    const int sw   = (l16 & 7) << 4;  // read-side XOR swizzle
    const int kcol = wave * 16 + l16; // this wave's k-strip column (QK B-op / P col)

    // ---- Q: all 64 rows of the block in registers (A-op: m=l16, k=quad*8+j)
    s16x8 aq[4][4];
    #pragma unroll
    for (int mt = 0; mt < 4; ++mt) {
        const u16* qp = qw + ((size_t)(b * SEQ + q0 + mt * 16 + l16) << 7);
        #pragma unroll
        for (int s = 0; s < 4; ++s)
            aq[mt][s] = *(const s16x8*)(qp + s * 32 + quad * 8);
    }

    const char* kb = kw + ((size_t)(b * NT) << 14);
    const char* vb = vw + ((size_t)(b * NT) << 14);

    float lsum[4][4];
    #pragma unroll
    for (int mt = 0; mt < 4; ++mt)
        #pragma unroll
        for (int r = 0; r < 4; ++r) lsum[mt][r] = 0.f;

    // =================== Pass 1: strip row-sums of exp ===================
    STAGE16K(kb, KOFF0);
    __syncthreads();
    int kof = KOFF0;
    for (int kt = 0; kt < NT; ++kt) {
        if (kt + 1 < NT) STAGE16K(kb + ((size_t)(kt + 1) << 14), kof ^ 16384);
        s16x8 bk[4];
        #pragma unroll
        for (int s = 0; s < 4; ++s)
            bk[s] = *(const s16x8*)(smem + kof +
                (((kcol << 8) + s * 64 + quad * 16) ^ sw));
        __builtin_amdgcn_s_setprio(1);
        f32x4 cm[4];
        #pragma unroll
        for (int mt = 0; mt < 4; ++mt) {
            f32x4 c = {0.f, 0.f, 0.f, 0.f};
            #pragma unroll
            for (int s = 0; s < 4; ++s)
                c = __builtin_amdgcn_mfma_f32_16x16x32_bf16(aq[mt][s], bk[s], c, 0, 0, 0);
            cm[mt] = c;
        }
        __builtin_amdgcn_s_setprio(0);
        #pragma unroll
        for (int mt = 0; mt < 4; ++mt) {
            float mk[4] = {0.f, 0.f, 0.f, 0.f};
            if (hm) {
                #pragma unroll
                for (int r = 0; r < 4; ++r)
                    mk[r] = mask[(size_t)(q0 + mt * 16 + quad * 4 + r) * SEQ
                                 + kt * BN + kcol] * L2E;
            }
            #pragma unroll
            for (int r = 0; r < 4; ++r)
                lsum[mt][r] += exp2f(cm[mt][r] * CS + mk[r]);
        }
        __syncthreads();
        kof ^= 16384;
    }

    // ---- combine strips: in-wave over l16, then cross-wave via 1KB LDS
    float* ls = (float*)(smem + POFF);   // ls[64][4] f32
    #pragma unroll
    for (int mt = 0; mt < 4; ++mt)
        #pragma unroll
        for (int r = 0; r < 4; ++r) {
            float s = lsum[mt][r];
            s += __shfl_xor(s, 1);
            s += __shfl_xor(s, 2);
            s += __shfl_xor(s, 4);
            s += __shfl_xor(s, 8);
            lsum[mt][r] = s;
        }
    if (l16 == 0) {
        #pragma unroll
        for (int mt = 0; mt < 4; ++mt)
            #pragma unroll
            for (int r = 0; r < 4; ++r)
                ls[(mt * 16 + quad * 4 + r) * 4 + wave] = lsum[mt][r];
    }
    __syncthreads();
    float linv[4][4];
    #pragma unroll
    for (int mt = 0; mt < 4; ++mt)
        #pragma unroll
        for (int r = 0; r < 4; ++r) {
            f32x4 t = *(const f32x4*)&ls[(mt * 16 + quad * 4 + r) * 4];
            linv[mt][r] = 1.0f / (t[0] + t[1] + t[2] + t[3]);
        }

    f32x4 acc[4][2];
    #pragma unroll
    for (int amt = 0; amt < 4; ++amt) {
        acc[amt][0] = (f32x4){0.f, 0.f, 0.f, 0.f};
        acc[amt][1] = (f32x4){0.f, 0.f, 0.f, 0.f};
    }

    // =================== Pass 2 ====================================================
    STAGE16K(kb, KOFF0);
    STAGE16K(vb, VOFF0);
    __syncthreads();   // also orders ls reads before first pp write (same LDS)
    int bof = 0;
    for (int kt = 0; kt < NT; ++kt) {
        if (kt + 1 < NT) {
            STAGE16K(kb + ((size_t)(kt + 1) << 14), KOFF0 + (bof ^ 16384));
            STAGE16K(vb + ((size_t)(kt + 1) << 14), VOFF0 + (bof ^ 16384));
        }
        s16x8 bk[4];
        #pragma unroll
        for (int s = 0; s < 4; ++s)
            bk[s] = *(const s16x8*)(smem + KOFF0 + bof +
                (((kcol << 8) + s * 64 + quad * 16) ^ sw));
        __builtin_amdgcn_s_setprio(1);
        f32x4 cm[4];
        #pragma unroll
        for (int mt = 0; mt < 4; ++mt) {
            f32x4 c = {0.f, 0.f, 0.f, 0.f};
            #pragma unroll
            for (int s = 0; s < 4; ++s)
                c = __builtin_amdgcn_mfma_f32_16x16x32_bf16(aq[mt][s], bk[s], c, 0, 0, 0);
            cm[mt] = c;
        }
        __builtin_amdgcn_s_setprio(0);
        #pragma unroll
        for (int mt = 0; mt < 4; ++mt) {
            float mk[4] = {0.f, 0.f, 0.f, 0.f};
            if (hm) {
                #pragma unroll
                for (int r = 0; r < 4; ++r)
                    mk[r] = mask[(size_t)(q0 + mt * 16 + quad * 4 + r) * SEQ
                                 + kt * BN + kcol] * L2E;
            }
            #pragma unroll
            for (int r = 0; r < 4; ++r) {
                float p = exp2f(cm[mt][r] * CS + mk[r]) * linv[mt][r];
                const int pr = mt * 16 + quad * 4 + r;
                // P -> LDS only (bf16). Global store happens post-PV, full-line.
                *(short*)(smem + POFF +
                    (((pr << 7) + (kcol << 1)) ^ ((pr & 7) << 4))) = f2bf(p);
            }
        }
        // light barrier: P visible to all waves; K/V DMA stays in flight
        __builtin_amdgcn_sched_barrier(0);
        asm volatile("s_waitcnt lgkmcnt(0)\n\ts_barrier" ::: "memory");
        __builtin_amdgcn_sched_barrier(0);

        // PV: A = P (full 64 rows), B = this wave's 32-d strip of V^T
        const int vbase = VOFF0 + bof;
        __builtin_amdgcn_s_setprio(1);
        #pragma unroll
        for (int s2 = 0; s2 < 2; ++s2) {
            const s16x8 bv0 = *(const s16x8*)(smem + vbase +
                ((((wave * 32 + l16) << 7) + s2 * 64 + quad * 16) ^ sw));
            const s16x8 bv1 = *(const s16x8*)(smem + vbase +
                ((((wave * 32 + 16 + l16) << 7) + s2 * 64 + quad * 16) ^ sw));
            #pragma unroll
            for (int amt = 0; amt < 4; ++amt) {
                const s16x8 pa = *(const s16x8*)(smem + POFF +
                    ((((amt * 16 + l16) << 7) + s2 * 64 + quad * 16) ^ sw));
                acc[amt][0] = __builtin_amdgcn_mfma_f32_16x16x32_bf16(pa, bv0, acc[amt][0], 0, 0, 0);
                acc[amt][1] = __builtin_amdgcn_mfma_f32_16x16x32_bf16(pa, bv1, acc[amt][1], 0, 0, 0);
            }
        }
        __builtin_amdgcn_s_setprio(0);

        // ---- store P tile to out_p: f32 from LDS bf16, 256B contiguous per
        // 16-lane group (2 full 128B lines per store instruction -> no RMW).
        #pragma unroll
        for (int i = 0; i < 4; ++i) {
            const int prw = wave * 16 + i * 4 + (lane >> 4);   // 0..63
            const int pcl = (lane & 15) * 4;                   // 0..60
            s16x4 pw = *(const s16x4*)(smem + POFF +
                (((prw << 7) + (pcl << 1)) ^ ((prw & 7) << 4)));
            f32x4 pf;
            #pragma unroll
            for (int j = 0; j < 4; ++j) {
                union { unsigned u; float f; } cv;
                cv.u = ((unsigned)(unsigned short)pw[j]) << 16;
                pf[j] = cv.f;
            }
            __builtin_nontemporal_store(pf, (f32x4*)
                &out_p[((size_t)(b * SEQ + q0 + prw) << 11) + kt * BN + pcl]);
        }

        __syncthreads();  // drains DMA for next tile; P LDS reads done before rewrite
        bof ^= 16384;
    }

    // ---- write O (fp32): rows amt*16+quad*4+r, cols wave*32+nt*16+l16
    #pragma unroll
    for (int amt = 0; amt < 4; ++amt)
        #pragma unroll
        for (int nt = 0; nt < 2; ++nt)
            #pragma unroll
            for (int r = 0; r < 4; ++r)
                __builtin_nontemporal_store(acc[amt][nt][r],
                    &out_o[((size_t)(b * SEQ + q0 + amt * 16 + quad * 4 + r) << 7)
                           + wave * 32 + nt * 16 + l16]);
}

extern "C" void kernel_launch(void* const* d_in, const int* in_sizes, int n_in,
                              void* d_out, int out_size, void* d_ws, size_t ws_size,
                              hipStream_t stream) {
    (void)in_sizes; (void)n_in; (void)out_size; (void)ws_size;
    const float* q    = (const float*)d_in[0];
    const float* k    = (const float*)d_in[1];
    const float* v    = (const float*)d_in[2];
    const float* mask = (const float*)d_in[3];
    float* out_o = (float*)d_out;                          // [16,2048,128]
    float* out_p = out_o + (size_t)BATCH * SEQ * DH;       // [16,2048,2048]

    char* ws   = (char*)d_ws;
    u16*  qw   = (u16*)ws;                                 // 8 MiB bf16 Q
    char* kw   = ws + ((size_t)8 << 20);                   // 8 MiB swizzled K tiles
    char* vw   = ws + ((size_t)16 << 20);                  // 8 MiB swizzled V^T tiles
    int*  flag = (int*)(ws + ((size_t)24 << 20));          // has_mask flag

    hipMemsetAsync(flag, 0, 4, stream);
    conv_qk<<<dim3(2048), dim3(256), 0, stream>>>(q, k, mask, qw, kw, flag);
    conv_v<<<dim3(NT, BATCH), dim3(256), 0, stream>>>(v, vw);

    static bool attr_done = false;
    if (!attr_done) {
        (void)hipFuncSetAttribute((const void*)attn_main,
                                  hipFuncAttributeMaxDynamicSharedMemorySize, 73728);
        attr_done = true;
    }
    attn_main<<<dim3(SEQ / BM, BATCH), dim3(256), 73728, stream>>>(
        qw, kw, vw, mask, flag, out_o, out_p);
}